// Round 10
// baseline (352.880 us; speedup 1.0000x reference)
//
#include <hip/hip_runtime.h>
#include <hip/hip_bf16.h>

// Problem constants
#define B_   16
#define C_   64
#define G_   256
#define P_   4096
#define W_   1024
#define H_   256
#define WQ_  256
#define M_   (B_ * P_)   // 65536 flattened (b,p) rows

typedef __attribute__((ext_vector_type(8))) _Float16 f16x8;  // MFMA A/B frag (4 VGPRs)
typedef __attribute__((ext_vector_type(4))) float    f32x4;  // MFMA C/D frag

__device__ __forceinline__ float h2f(ushort u) {
    union { ushort u; _Float16 h; } cv; cv.u = u;
    return (float)cv.h;
}

// ---------------------------------------------------------------------------
// convT16: src[K][N] fp32 -> dst[N][K] fp16 (transposed, RNE via v_cvt_f16_f32)
// grid = (K/64)*(N/64), 256 threads
// ---------------------------------------------------------------------------
__global__ __launch_bounds__(256) void convT16_kernel(
    const float* __restrict__ src, ushort* __restrict__ dst, int K, int N)
{
    __shared__ float tile[64][65];
    const int nb = N >> 6;
    const int k0 = (blockIdx.x / nb) * 64;
    const int n0 = (blockIdx.x % nb) * 64;
    const int t = threadIdx.x;
    #pragma unroll
    for (int i = 0; i < 16; ++i) {
        int e = i * 256 + t;
        int kr = e >> 6, nc = e & 63;
        tile[nc][kr] = src[(size_t)(k0 + kr) * N + n0 + nc];
    }
    __syncthreads();
    #pragma unroll
    for (int i = 0; i < 16; ++i) {
        int e = i * 256 + t;
        int nc = e >> 6, kr = e & 63;
        union { _Float16 h; ushort u; } cv;
        cv.h = (_Float16)tile[nc][kr];
        dst[(size_t)(n0 + nc) * K + k0 + kr] = cv.u;
    }
}

// ---------------------------------------------------------------------------
// Kernel 1: prep — c = cx@Wc+bc, g = gx@Wg+bg, base = c@W1c + g@W1g + b1
// ---------------------------------------------------------------------------
__global__ __launch_bounds__(256) void prep_kernel(
    const float* __restrict__ cx, const float* __restrict__ gx,
    const float* __restrict__ Wc, const float* __restrict__ bc,
    const float* __restrict__ Wg, const float* __restrict__ bg,
    const float* __restrict__ W1, const float* __restrict__ b1,
    float* __restrict__ base_out)
{
    const int b = blockIdx.x;
    const int t = threadIdx.x;
    __shared__ float cxl[C_], gxl[G_], cl[C_], gl[G_];

    if (t < C_) cxl[t] = cx[b * C_ + t];
    gxl[t] = gx[b * G_ + t];
    __syncthreads();

    if (t < C_) {
        float acc = bc[t];
        #pragma unroll 4
        for (int i = 0; i < C_; ++i) acc += cxl[i] * Wc[i * C_ + t];
        cl[t] = acc;
    }
    {
        float acc = bg[t];
        #pragma unroll 4
        for (int i = 0; i < G_; ++i) acc += gxl[i] * Wg[i * G_ + t];
        gl[t] = acc;
    }
    __syncthreads();

    float acc = b1[t];
    #pragma unroll 4
    for (int i = 0; i < C_; ++i) acc += cl[i] * W1[i * H_ + t];
    #pragma unroll 4
    for (int i = 0; i < G_; ++i) acc += gl[i] * W1[(C_ + i) * H_ + t];
    base_out[b * H_ + t] = acc;
}

// ---------------------------------------------------------------------------
// Kernel 2: FUSED w GEMM + scores.
// Stage 1 (as R9): M=65536,K=1024,N=256; BM=128, BN=256(all), BK=64; 512 thr,
//   8 waves (2Mx4N); fp16 MFMA; w written to global as fp16.
// Stage 2 (new): scores for the SAME 128 rows — w tile read back from L2
//   (own writes, first-touch lines -> no stale L1), W1wT read L2-direct.
//   NO LDS staging, NO barriers in the stage-2 K-loop. Fused relu·W2 epilogue.
// grid = M/128 = 512
// ---------------------------------------------------------------------------
__global__ __launch_bounds__(512, 2) void gemm_w_fused(
    const float* __restrict__ A,      // wx  M x 1024 fp32
    const ushort* __restrict__ BT,    // WwT fp16 [256][1024]
    const float* __restrict__ bw,
    const ushort* __restrict__ W1T,   // W1wT fp16 [256 h][256 q]
    const float* __restrict__ base_,  // B_ x 256
    const float* __restrict__ W2,     // 256
    const float* __restrict__ b2,     // 1
    ushort* __restrict__ Cout,        // w  M x 256 fp16
    float* __restrict__ scores)       // M
{
    __shared__ __align__(16) ushort Ah[128 * 64];   // 16 KB
    __shared__ __align__(16) ushort Bh[256 * 64];   // 32 KB
    __shared__ float red2[4][128];                  // 2 KB
    const int t = threadIdx.x;
    const int row0 = blockIdx.x * 128;
    const int b = blockIdx.x >> 5;                  // 32 blocks per batch
    const int lane = t & 63, wave = t >> 6;
    const int wm = wave >> 2, wn = wave & 3;        // 2M x 4N waves
    const int l15 = lane & 15, lq = lane >> 4;

    const int s_ar = t >> 2;            // A row 0..127
    const int s_ak = (t & 3) * 16;      // A k chunk start (16 floats)
    const int s_bc = t >> 1;            // B col 0..255
    const int s_bk = (t & 1) * 32;      // B k half (32 halves)

    f32x4 acc[4][4];
    #pragma unroll
    for (int m = 0; m < 4; ++m)
        #pragma unroll
        for (int n = 0; n < 4; ++n) acc[m][n] = (f32x4){0.f, 0.f, 0.f, 0.f};

    // ---------------- stage 1: w = wx @ Ww + bw ----------------
    for (int k0 = 0; k0 < W_; k0 += 64) {
        if (k0) __syncthreads();
        {
            const float* ap = A + (size_t)(row0 + s_ar) * W_ + k0 + s_ak;
            const float4 v0 = *(const float4*)(ap + 0);
            const float4 v1 = *(const float4*)(ap + 4);
            const float4 v2 = *(const float4*)(ap + 8);
            const float4 v3 = *(const float4*)(ap + 12);
            f16x8 h0, h1;
            h0[0] = (_Float16)v0.x; h0[1] = (_Float16)v0.y;
            h0[2] = (_Float16)v0.z; h0[3] = (_Float16)v0.w;
            h0[4] = (_Float16)v1.x; h0[5] = (_Float16)v1.y;
            h0[6] = (_Float16)v1.z; h0[7] = (_Float16)v1.w;
            h1[0] = (_Float16)v2.x; h1[1] = (_Float16)v2.y;
            h1[2] = (_Float16)v2.z; h1[3] = (_Float16)v2.w;
            h1[4] = (_Float16)v3.x; h1[5] = (_Float16)v3.y;
            h1[6] = (_Float16)v3.z; h1[7] = (_Float16)v3.w;
            const int base = s_ar * 128 + s_ak * 2;
            const int swz  = (s_ar & 7) << 4;
            *(f16x8*)((char*)Ah + (base ^ swz)) = h0;
            *(f16x8*)((char*)Ah + ((base + 16) ^ swz)) = h1;
        }
        #pragma unroll
        for (int i = 0; i < 4; ++i) {
            const int kk = s_bk + i * 8;
            const int byte = (s_bc * 128 + kk * 2) ^ ((s_bc & 7) << 4);
            *(uint4*)((char*)Bh + byte) =
                *(const uint4*)(BT + (size_t)s_bc * W_ + k0 + kk);
        }
        __syncthreads();

        #pragma unroll
        for (int ks = 0; ks < 2; ++ks) {
            f16x8 af[4], bf[4];
            #pragma unroll
            for (int m = 0; m < 4; ++m) {
                const int r = wm * 64 + m * 16 + l15;
                const int byte = (r * 128 + ks * 64 + lq * 16) ^ ((r & 7) << 4);
                af[m] = *(const f16x8*)((const char*)Ah + byte);
            }
            #pragma unroll
            for (int n = 0; n < 4; ++n) {
                const int c = wn * 64 + n * 16 + l15;
                const int byte = (c * 128 + ks * 64 + lq * 16) ^ ((c & 7) << 4);
                bf[n] = *(const f16x8*)((const char*)Bh + byte);
            }
            #pragma unroll
            for (int m = 0; m < 4; ++m)
                #pragma unroll
                for (int n = 0; n < 4; ++n)
                    acc[m][n] = __builtin_amdgcn_mfma_f32_16x16x32_f16(
                        af[m], bf[n], acc[m][n], 0, 0, 0);
        }
    }

    // epilogue 1: w16[row][col] = fp16(acc + bw[col]) -> global
    {
        float bwv[4];
        #pragma unroll
        for (int n = 0; n < 4; ++n) bwv[n] = bw[wn * 64 + n * 16 + l15];
        #pragma unroll
        for (int m = 0; m < 4; ++m)
            #pragma unroll
            for (int reg = 0; reg < 4; ++reg) {
                const size_t r = (size_t)row0 + wm * 64 + m * 16 + lq * 4 + reg;
                #pragma unroll
                for (int n = 0; n < 4; ++n) {
                    union { _Float16 h; ushort u; } cv;
                    cv.h = (_Float16)(acc[m][n][reg] + bwv[n]);
                    Cout[r * WQ_ + wn * 64 + n * 16 + l15] = cv.u;
                }
            }
    }

    // make w16 stores visible; lines are first-touch for reads (no stale L1)
    __threadfence();
    __syncthreads();

    // ---------------- stage 2: scores = relu(base + w @ W1w) · W2 + b2 ------
    f32x4 acc2[4][4];
    #pragma unroll
    for (int m = 0; m < 4; ++m)
        #pragma unroll
        for (int n = 0; n < 4; ++n) acc2[m][n] = (f32x4){0.f, 0.f, 0.f, 0.f};

    for (int k2 = 0; k2 < WQ_; k2 += 32) {
        f16x8 af[4], bf[4];
        #pragma unroll
        for (int m = 0; m < 4; ++m) {
            const size_t r = (size_t)row0 + wm * 64 + m * 16 + l15;
            af[m] = *(const f16x8*)(Cout + r * WQ_ + k2 + lq * 8);
        }
        #pragma unroll
        for (int n = 0; n < 4; ++n) {
            const int c = wn * 64 + n * 16 + l15;
            bf[n] = *(const f16x8*)(W1T + (size_t)c * WQ_ + k2 + lq * 8);
        }
        #pragma unroll
        for (int m = 0; m < 4; ++m)
            #pragma unroll
            for (int n = 0; n < 4; ++n)
                acc2[m][n] = __builtin_amdgcn_mfma_f32_16x16x32_f16(
                    af[m], bf[n], acc2[m][n], 0, 0, 0);
    }

    // epilogue 2: reduce relu(acc2+base)·W2 over h
    {
        float basev[4], w2v[4];
        #pragma unroll
        for (int n = 0; n < 4; ++n) {
            const int col = wn * 64 + n * 16 + l15;
            basev[n] = base_[b * H_ + col];
            w2v[n] = W2[col];
        }
        #pragma unroll
        for (int m = 0; m < 4; ++m)
            #pragma unroll
            for (int reg = 0; reg < 4; ++reg) {
                float s = 0.f;
                #pragma unroll
                for (int n = 0; n < 4; ++n) {
                    float h = acc2[m][n][reg] + basev[n];
                    h = fmaxf(h, 0.f);
                    s += h * w2v[n];
                }
                s += __shfl_xor(s, 1, 64);
                s += __shfl_xor(s, 2, 64);
                s += __shfl_xor(s, 4, 64);
                s += __shfl_xor(s, 8, 64);
                if (l15 == 0) red2[wn][wm * 64 + m * 16 + lq * 4 + reg] = s;
            }
        __syncthreads();
        if (t < 128) {
            scores[row0 + t] =
                red2[0][t] + red2[1][t] + red2[2][t] + red2[3][t] + b2[0];
        }
    }
}

// ---------------------------------------------------------------------------
// Kernel 4: softmax stats per b — m = max_p s, z = sum_p exp(s-m)
// ---------------------------------------------------------------------------
__global__ __launch_bounds__(256) void softmax_stats_kernel(
    const float* __restrict__ scores, float* __restrict__ mz)
{
    const int b = blockIdx.x;
    const int t = threadIdx.x;
    __shared__ float red[8];

    float m = -1e30f;
    for (int p = t; p < P_; p += 256) m = fmaxf(m, scores[b * P_ + p]);
    #pragma unroll
    for (int d = 1; d < 64; d <<= 1) m = fmaxf(m, __shfl_xor(m, d, 64));
    if ((t & 63) == 0) red[t >> 6] = m;
    __syncthreads();
    if (t == 0) red[4] = fmaxf(fmaxf(red[0], red[1]), fmaxf(red[2], red[3]));
    __syncthreads();
    m = red[4];
    __syncthreads();

    float z = 0.f;
    for (int p = t; p < P_; p += 256) z += expf(scores[b * P_ + p] - m);
    #pragma unroll
    for (int d = 1; d < 64; d <<= 1) z += __shfl_xor(z, d, 64);
    if ((t & 63) == 0) red[t >> 6] = z;
    __syncthreads();
    if (t == 0) { mz[2 * b] = m; mz[2 * b + 1] = red[0] + red[1] + red[2] + red[3]; }
}

// ---------------------------------------------------------------------------
// Kernel 5: weighted partial sums over 128-row slices (fp16 w, ushort8 loads)
// ---------------------------------------------------------------------------
__global__ __launch_bounds__(256) void weighted_partial_kernel(
    const ushort* __restrict__ wmat16, const float* __restrict__ scores,
    const float* __restrict__ mz, float* __restrict__ part)
{
    const int blk = blockIdx.x;
    const int b   = blk >> 5;
    const int sl  = blk & 31;
    const int t   = threadIdx.x;
    const int rg  = t >> 5;            // 0..7
    const int q8  = (t & 31) * 8;      // 0..248
    const float m = mz[2 * b];
    __shared__ float red[8][WQ_];

    float acc[8];
    #pragma unroll
    for (int j = 0; j < 8; ++j) acc[j] = 0.f;

    const int p0 = sl * 128 + rg * 16;
    for (int p = p0; p < p0 + 16; ++p) {
        const float e = expf(scores[b * P_ + p] - m);
        const uint4 raw = *(const uint4*)(wmat16 + ((size_t)b * P_ + p) * WQ_ + q8);
        const ushort* u = (const ushort*)&raw;
        #pragma unroll
        for (int j = 0; j < 8; ++j) acc[j] += e * h2f(u[j]);
    }
    #pragma unroll
    for (int j = 0; j < 8; ++j) red[rg][q8 + j] = acc[j];
    __syncthreads();
    float s = 0.f;
    #pragma unroll
    for (int g = 0; g < 8; ++g) s += red[g][t];
    part[(size_t)(b * 32 + sl) * WQ_ + t] = s;
}

// ---------------------------------------------------------------------------
// Kernel 6: finalize
// ---------------------------------------------------------------------------
__global__ __launch_bounds__(256) void finalize_kernel(
    const float* __restrict__ part, const float* __restrict__ mz,
    float* __restrict__ out)
{
    const int b = blockIdx.x;
    const int t = threadIdx.x;
    const float z = mz[2 * b + 1];
    float acc = 0.f;
    #pragma unroll
    for (int sl = 0; sl < 32; ++sl) acc += part[(size_t)(b * 32 + sl) * WQ_ + t];
    out[b * WQ_ + t] = acc / z;
}

// ---------------------------------------------------------------------------
extern "C" void kernel_launch(void* const* d_in, const int* in_sizes, int n_in,
                              void* d_out, int out_size, void* d_ws, size_t ws_size,
                              hipStream_t stream) {
    const float* cx = (const float*)d_in[0];
    const float* gx = (const float*)d_in[1];
    const float* wx = (const float*)d_in[2];
    const float* Wc = (const float*)d_in[3];
    const float* bc = (const float*)d_in[4];
    const float* Wg = (const float*)d_in[5];
    const float* bg = (const float*)d_in[6];
    const float* Ww = (const float*)d_in[7];
    const float* bw = (const float*)d_in[8];
    const float* W1 = (const float*)d_in[9];
    const float* b1 = (const float*)d_in[10];
    const float* W2 = (const float*)d_in[11];
    const float* b2 = (const float*)d_in[12];
    float* out = (float*)d_out;

    // workspace layout
    float* ws        = (float*)d_ws;
    ushort* ws_w16   = (ushort*)ws;                      // M_*WQ_ fp16 (32 MB)
    float* ws_scores = ws + (size_t)M_ * WQ_ / 2;        // M_
    float* ws_base   = ws_scores + M_;                   // B_*H_
    float* ws_mz     = ws_base + B_ * H_;                // 2*B_
    float* ws_part   = ws_mz + 2 * B_;                   // B_*32*WQ_
    ushort* WwT16    = (ushort*)(ws_part + B_ * 32 * WQ_);   // W_*WQ_ fp16
    ushort* W1T16    = WwT16 + (size_t)W_ * WQ_;             // H_*H_ fp16

    convT16_kernel<<<(W_ / 64) * (WQ_ / 64), 256, 0, stream>>>(Ww, WwT16, W_, WQ_);
    convT16_kernel<<<(H_ / 64) * (H_ / 64), 256, 0, stream>>>(
        W1 + (size_t)(C_ + G_) * H_, W1T16, H_, H_);

    prep_kernel<<<B_, 256, 0, stream>>>(cx, gx, Wc, bc, Wg, bg, W1, b1, ws_base);

    gemm_w_fused<<<M_ / 128, 512, 0, stream>>>(
        wx, WwT16, bw, W1T16, ws_base, W2, b2, ws_w16, ws_scores);

    softmax_stats_kernel<<<B_, 256, 0, stream>>>(ws_scores, ws_mz);

    weighted_partial_kernel<<<B_ * 32, 256, 0, stream>>>(ws_w16, ws_scores, ws_mz, ws_part);

    finalize_kernel<<<B_, 256, 0, stream>>>(ws_part, ws_mz, out);
}

// Round 11
// 181.840 us; speedup vs baseline: 1.9406x; 1.9406x over previous
//
#include <hip/hip_runtime.h>
#include <hip/hip_bf16.h>

// Problem constants
#define B_   16
#define C_   64
#define G_   256
#define P_   4096
#define W_   1024
#define H_   256
#define WQ_  256
#define M_   (B_ * P_)   // 65536 flattened (b,p) rows

typedef __attribute__((ext_vector_type(8))) _Float16 f16x8;  // MFMA A/B frag (4 VGPRs)
typedef __attribute__((ext_vector_type(4))) float    f32x4;  // MFMA C/D frag

__device__ __forceinline__ float h2f(ushort u) {
    union { ushort u; _Float16 h; } cv; cv.u = u;
    return (float)cv.h;
}

// async global->LDS, 16B per lane (dest = wave-uniform base + lane*16)
#define GLOAD16(gsrc, ldst)                                                  \
    __builtin_amdgcn_global_load_lds(                                        \
        (const __attribute__((address_space(1))) unsigned int*)(gsrc),       \
        (__attribute__((address_space(3))) unsigned int*)(ldst), 16, 0, 0)

// Inverse of the 64B-row XOR swizzle  p = l ^ (((l>>6)&7)<<4):
//   l4 = p4^p6^p8, l5 = p5^p7, l6 = p6^p8  (bits >6 and <4 unchanged)
__device__ __forceinline__ int inv_swz64(int o) {
    const int b8 = (o >> 8) & 1, b7 = (o >> 7) & 1, b6 = (o >> 6) & 1;
    const int b5 = (o >> 5) & 1, b4 = (o >> 4) & 1;
    const int l6 = b6 ^ b8, l5 = b5 ^ b7, l4 = b4 ^ l6;
    return (o & ~0x70) | (l6 << 6) | (l5 << 5) | (l4 << 4);
}

// ---------------------------------------------------------------------------
// convT16: src[K][N] fp32 -> dst[N][K] fp16 (transposed, RNE)
// ---------------------------------------------------------------------------
__global__ __launch_bounds__(256) void convT16_kernel(
    const float* __restrict__ src, ushort* __restrict__ dst, int K, int N)
{
    __shared__ float tile[64][65];
    const int nb = N >> 6;
    const int k0 = (blockIdx.x / nb) * 64;
    const int n0 = (blockIdx.x % nb) * 64;
    const int t = threadIdx.x;
    #pragma unroll
    for (int i = 0; i < 16; ++i) {
        int e = i * 256 + t;
        int kr = e >> 6, nc = e & 63;
        tile[nc][kr] = src[(size_t)(k0 + kr) * N + n0 + nc];
    }
    __syncthreads();
    #pragma unroll
    for (int i = 0; i < 16; ++i) {
        int e = i * 256 + t;
        int nc = e >> 6, kr = e & 63;
        union { _Float16 h; ushort u; } cv;
        cv.h = (_Float16)tile[nc][kr];
        dst[(size_t)(n0 + nc) * K + k0 + kr] = cv.u;
    }
}

// ---------------------------------------------------------------------------
// Kernel 1: prep — c = cx@Wc+bc, g = gx@Wg+bg, base = c@W1c + g@W1g + b1
// ---------------------------------------------------------------------------
__global__ __launch_bounds__(256) void prep_kernel(
    const float* __restrict__ cx, const float* __restrict__ gx,
    const float* __restrict__ Wc, const float* __restrict__ bc,
    const float* __restrict__ Wg, const float* __restrict__ bg,
    const float* __restrict__ W1, const float* __restrict__ b1,
    float* __restrict__ base_out)
{
    const int b = blockIdx.x;
    const int t = threadIdx.x;
    __shared__ float cxl[C_], gxl[G_], cl[C_], gl[G_];

    if (t < C_) cxl[t] = cx[b * C_ + t];
    gxl[t] = gx[b * G_ + t];
    __syncthreads();

    if (t < C_) {
        float acc = bc[t];
        #pragma unroll 4
        for (int i = 0; i < C_; ++i) acc += cxl[i] * Wc[i * C_ + t];
        cl[t] = acc;
    }
    {
        float acc = bg[t];
        #pragma unroll 4
        for (int i = 0; i < G_; ++i) acc += gxl[i] * Wg[i * G_ + t];
        gl[t] = acc;
    }
    __syncthreads();

    float acc = b1[t];
    #pragma unroll 4
    for (int i = 0; i < C_; ++i) acc += cl[i] * W1[i * H_ + t];
    #pragma unroll 4
    for (int i = 0; i < G_; ++i) acc += gl[i] * W1[(C_ + i) * H_ + t];
    base_out[b * H_ + t] = acc;
}

// ---------------------------------------------------------------------------
// Kernel 2: w GEMM (R9 structure). B staging now via global_load_lds:
// linear LDS dest, XOR-swizzle pre-applied to the SOURCE address (rule #21;
// 128B rows -> mask stays in-row). A keeps reg-staged fp32->fp16 convert.
// NO __threadfence anywhere (R10 lesson: device fence trashes per-XCD L2s).
// grid = M/128 = 512, 512 thr, 8 waves (2Mx4N).
// ---------------------------------------------------------------------------
__global__ __launch_bounds__(512, 2) void gemm_w_mfma(
    const float* __restrict__ A,      // wx  M x 1024 fp32
    const ushort* __restrict__ BT,    // WwT fp16 [256][1024]
    const float* __restrict__ bw,
    ushort* __restrict__ Cout)        // w  M x 256 fp16
{
    __shared__ __align__(16) ushort Ah[128 * 64];   // 16 KB, 128B rows
    __shared__ __align__(16) ushort Bh[256 * 64];   // 32 KB, 128B rows
    const int t = threadIdx.x;
    const int row0 = blockIdx.x * 128;
    const int lane = t & 63, wave = t >> 6;
    const int wm = wave >> 2, wn = wave & 3;
    const int l15 = lane & 15, lq = lane >> 4;

    const int s_ar = t >> 2;            // A row 0..127
    const int s_ak = (t & 3) * 16;      // A k chunk start (16 floats)

    // B staging precompute: linear dest o, pre-swizzled source
    const ushort* srcB0; const ushort* srcB1; const ushort* srcB2; const ushort* srcB3;
    char *dstB0, *dstB1, *dstB2, *dstB3;
    {
        const int o0 = t * 16, o1 = o0 + 8192, o2 = o0 + 16384, o3 = o0 + 24576;
        const int c0 = o0 >> 7, c1 = o1 >> 7, c2 = o2 >> 7, c3 = o3 >> 7;
        const int x0 = o0 & 127, x1 = o1 & 127, x2 = o2 & 127, x3 = o3 & 127;
        srcB0 = BT + (size_t)c0 * W_ + ((x0 ^ ((c0 & 7) << 4)) >> 1);
        srcB1 = BT + (size_t)c1 * W_ + ((x1 ^ ((c1 & 7) << 4)) >> 1);
        srcB2 = BT + (size_t)c2 * W_ + ((x2 ^ ((c2 & 7) << 4)) >> 1);
        srcB3 = BT + (size_t)c3 * W_ + ((x3 ^ ((c3 & 7) << 4)) >> 1);
        dstB0 = (char*)Bh + o0; dstB1 = (char*)Bh + o1;
        dstB2 = (char*)Bh + o2; dstB3 = (char*)Bh + o3;
    }

    f32x4 acc[4][4];
    #pragma unroll
    for (int m = 0; m < 4; ++m)
        #pragma unroll
        for (int n = 0; n < 4; ++n) acc[m][n] = (f32x4){0.f, 0.f, 0.f, 0.f};

    for (int k0 = 0; k0 < W_; k0 += 64) {
        if (k0) __syncthreads();
        // B: 4 async copies, no VGPR round trip
        GLOAD16(srcB0 + k0, dstB0);
        GLOAD16(srcB1 + k0, dstB1);
        GLOAD16(srcB2 + k0, dstB2);
        GLOAD16(srcB3 + k0, dstB3);
        // A: 16 fp32 -> 16 fp16 (RNE), two b128 writes (swizzled)
        {
            const float* ap = A + (size_t)(row0 + s_ar) * W_ + k0 + s_ak;
            const float4 v0 = *(const float4*)(ap + 0);
            const float4 v1 = *(const float4*)(ap + 4);
            const float4 v2 = *(const float4*)(ap + 8);
            const float4 v3 = *(const float4*)(ap + 12);
            f16x8 h0, h1;
            h0[0] = (_Float16)v0.x; h0[1] = (_Float16)v0.y;
            h0[2] = (_Float16)v0.z; h0[3] = (_Float16)v0.w;
            h0[4] = (_Float16)v1.x; h0[5] = (_Float16)v1.y;
            h0[6] = (_Float16)v1.z; h0[7] = (_Float16)v1.w;
            h1[0] = (_Float16)v2.x; h1[1] = (_Float16)v2.y;
            h1[2] = (_Float16)v2.z; h1[3] = (_Float16)v2.w;
            h1[4] = (_Float16)v3.x; h1[5] = (_Float16)v3.y;
            h1[6] = (_Float16)v3.z; h1[7] = (_Float16)v3.w;
            const int base = s_ar * 128 + s_ak * 2;
            const int swz  = (s_ar & 7) << 4;
            *(f16x8*)((char*)Ah + (base ^ swz)) = h0;
            *(f16x8*)((char*)Ah + ((base + 16) ^ swz)) = h1;
        }
        __syncthreads();

        #pragma unroll
        for (int ks = 0; ks < 2; ++ks) {
            f16x8 af[4], bf[4];
            #pragma unroll
            for (int m = 0; m < 4; ++m) {
                const int r = wm * 64 + m * 16 + l15;
                const int byte = (r * 128 + ks * 64 + lq * 16) ^ ((r & 7) << 4);
                af[m] = *(const f16x8*)((const char*)Ah + byte);
            }
            #pragma unroll
            for (int n = 0; n < 4; ++n) {
                const int c = wn * 64 + n * 16 + l15;
                const int byte = (c * 128 + ks * 64 + lq * 16) ^ ((c & 7) << 4);
                bf[n] = *(const f16x8*)((const char*)Bh + byte);
            }
            #pragma unroll
            for (int m = 0; m < 4; ++m)
                #pragma unroll
                for (int n = 0; n < 4; ++n)
                    acc[m][n] = __builtin_amdgcn_mfma_f32_16x16x32_f16(
                        af[m], bf[n], acc[m][n], 0, 0, 0);
        }
    }

    // epilogue: w16[row][col] = fp16(acc + bw[col])
    float bwv[4];
    #pragma unroll
    for (int n = 0; n < 4; ++n) bwv[n] = bw[wn * 64 + n * 16 + l15];
    #pragma unroll
    for (int m = 0; m < 4; ++m)
        #pragma unroll
        for (int reg = 0; reg < 4; ++reg) {
            const size_t r = (size_t)row0 + wm * 64 + m * 16 + lq * 4 + reg;
            #pragma unroll
            for (int n = 0; n < 4; ++n) {
                union { _Float16 h; ushort u; } cv;
                cv.h = (_Float16)(acc[m][n][reg] + bwv[n]);
                Cout[r * WQ_ + wn * 64 + n * 16 + l15] = cv.u;
            }
        }
}

// ---------------------------------------------------------------------------
// Kernel 3: scores — BOTH operands fp16: full global_load_lds staging
// (linear dest; source address carries the inverse of the 64B-row swizzle).
// Read side and math identical to R9 -> bit-identical output.
// grid = M/128 = 512, 512 thr, 8 waves (2x4), BK=32.
// ---------------------------------------------------------------------------
__global__ __launch_bounds__(512) void gemm_scores_mfma(
    const ushort* __restrict__ A16,   // w M x 256 fp16
    const ushort* __restrict__ BT,    // W1wT fp16 [256][256]
    const float* __restrict__ base_,  // B_ x 256
    const float* __restrict__ W2,     // 256
    const float* __restrict__ b2,     // 1
    float* __restrict__ scores)       // M
{
    __shared__ __align__(16) ushort Ah[128 * 32];   // 8 KB, 64B rows
    __shared__ __align__(16) ushort Bh[256 * 32];   // 16 KB, 64B rows
    __shared__ float red[4][128];
    const int t = threadIdx.x;
    const int row0 = blockIdx.x * 128;
    const int b = blockIdx.x >> 5;
    const int lane = t & 63, wave = t >> 6;
    const int wm = wave >> 2, wn = wave & 3;
    const int l15 = lane & 15, lq = lane >> 4;

    // staging precompute: physical linear o -> logical (row, k) via inv_swz64
    const int oA = t * 16;
    const int lA = inv_swz64(oA);
    const ushort* srcA = A16 + (size_t)(row0 + (lA >> 6)) * H_ + ((lA & 63) >> 1);
    char* dstA = (char*)Ah + oA;

    const int oB0 = t * 16, oB1 = t * 16 + 8192;
    const int lB0 = inv_swz64(oB0), lB1 = inv_swz64(oB1);
    const ushort* srcB0 = BT + (size_t)(lB0 >> 6) * H_ + ((lB0 & 63) >> 1);
    const ushort* srcB1 = BT + (size_t)(lB1 >> 6) * H_ + ((lB1 & 63) >> 1);
    char* dstB0 = (char*)Bh + oB0;
    char* dstB1 = (char*)Bh + oB1;

    f32x4 acc[4][4];
    #pragma unroll
    for (int m = 0; m < 4; ++m)
        #pragma unroll
        for (int n = 0; n < 4; ++n) acc[m][n] = (f32x4){0.f, 0.f, 0.f, 0.f};

    for (int k0 = 0; k0 < H_; k0 += 32) {
        if (k0) __syncthreads();
        GLOAD16(srcA + k0, dstA);
        GLOAD16(srcB0 + k0, dstB0);
        GLOAD16(srcB1 + k0, dstB1);
        __syncthreads();

        f16x8 af[4], bf[4];
        #pragma unroll
        for (int m = 0; m < 4; ++m) {
            const int r = wm * 64 + m * 16 + l15;
            const int byte = (r * 64 + lq * 16) ^ ((r & 7) << 4);
            af[m] = *(const f16x8*)((const char*)Ah + byte);
        }
        #pragma unroll
        for (int n = 0; n < 4; ++n) {
            const int c = wn * 64 + n * 16 + l15;
            const int byte = (c * 64 + lq * 16) ^ ((c & 7) << 4);
            bf[n] = *(const f16x8*)((const char*)Bh + byte);
        }
        #pragma unroll
        for (int m = 0; m < 4; ++m)
            #pragma unroll
            for (int n = 0; n < 4; ++n)
                acc[m][n] = __builtin_amdgcn_mfma_f32_16x16x32_f16(
                    af[m], bf[n], acc[m][n], 0, 0, 0);
    }

    // epilogue: scores[row] = sum_h relu(acc + base) * W2  (+ b2)
    float basev[4], w2v[4];
    #pragma unroll
    for (int n = 0; n < 4; ++n) {
        const int col = wn * 64 + n * 16 + l15;
        basev[n] = base_[b * H_ + col];
        w2v[n] = W2[col];
    }
    __syncthreads();
    #pragma unroll
    for (int m = 0; m < 4; ++m)
        #pragma unroll
        for (int reg = 0; reg < 4; ++reg) {
            float s = 0.f;
            #pragma unroll
            for (int n = 0; n < 4; ++n) {
                float h = acc[m][n][reg] + basev[n];
                h = fmaxf(h, 0.f);
                s += h * w2v[n];
            }
            s += __shfl_xor(s, 1, 64);
            s += __shfl_xor(s, 2, 64);
            s += __shfl_xor(s, 4, 64);
            s += __shfl_xor(s, 8, 64);
            if (l15 == 0) red[wn][wm * 64 + m * 16 + lq * 4 + reg] = s;
        }
    __syncthreads();
    if (t < 128) {
        scores[row0 + t] = red[0][t] + red[1][t] + red[2][t] + red[3][t] + b2[0];
    }
}

// ---------------------------------------------------------------------------
// Kernel 4: softmax stats per b — m = max_p s, z = sum_p exp(s-m)
// ---------------------------------------------------------------------------
__global__ __launch_bounds__(256) void softmax_stats_kernel(
    const float* __restrict__ scores, float* __restrict__ mz)
{
    const int b = blockIdx.x;
    const int t = threadIdx.x;
    __shared__ float red[8];

    float m = -1e30f;
    for (int p = t; p < P_; p += 256) m = fmaxf(m, scores[b * P_ + p]);
    #pragma unroll
    for (int d = 1; d < 64; d <<= 1) m = fmaxf(m, __shfl_xor(m, d, 64));
    if ((t & 63) == 0) red[t >> 6] = m;
    __syncthreads();
    if (t == 0) red[4] = fmaxf(fmaxf(red[0], red[1]), fmaxf(red[2], red[3]));
    __syncthreads();
    m = red[4];
    __syncthreads();

    float z = 0.f;
    for (int p = t; p < P_; p += 256) z += expf(scores[b * P_ + p] - m);
    #pragma unroll
    for (int d = 1; d < 64; d <<= 1) z += __shfl_xor(z, d, 64);
    if ((t & 63) == 0) red[t >> 6] = z;
    __syncthreads();
    if (t == 0) { mz[2 * b] = m; mz[2 * b + 1] = red[0] + red[1] + red[2] + red[3]; }
}

// ---------------------------------------------------------------------------
// Kernel 5: weighted partial sums over 128-row slices (fp16 w, ushort8 loads)
// ---------------------------------------------------------------------------
__global__ __launch_bounds__(256) void weighted_partial_kernel(
    const ushort* __restrict__ wmat16, const float* __restrict__ scores,
    const float* __restrict__ mz, float* __restrict__ part)
{
    const int blk = blockIdx.x;
    const int b   = blk >> 5;
    const int sl  = blk & 31;
    const int t   = threadIdx.x;
    const int rg  = t >> 5;            // 0..7
    const int q8  = (t & 31) * 8;      // 0..248
    const float m = mz[2 * b];
    __shared__ float red[8][WQ_];

    float acc[8];
    #pragma unroll
    for (int j = 0; j < 8; ++j) acc[j] = 0.f;

    const int p0 = sl * 128 + rg * 16;
    for (int p = p0; p < p0 + 16; ++p) {
        const float e = expf(scores[b * P_ + p] - m);
        const uint4 raw = *(const uint4*)(wmat16 + ((size_t)b * P_ + p) * WQ_ + q8);
        const ushort* u = (const ushort*)&raw;
        #pragma unroll
        for (int j = 0; j < 8; ++j) acc[j] += e * h2f(u[j]);
    }
    #pragma unroll
    for (int j = 0; j < 8; ++j) red[rg][q8 + j] = acc[j];
    __syncthreads();
    float s = 0.f;
    #pragma unroll
    for (int g = 0; g < 8; ++g) s += red[g][t];
    part[(size_t)(b * 32 + sl) * WQ_ + t] = s;
}

// ---------------------------------------------------------------------------
// Kernel 6: finalize
// ---------------------------------------------------------------------------
__global__ __launch_bounds__(256) void finalize_kernel(
    const float* __restrict__ part, const float* __restrict__ mz,
    float* __restrict__ out)
{
    const int b = blockIdx.x;
    const int t = threadIdx.x;
    const float z = mz[2 * b + 1];
    float acc = 0.f;
    #pragma unroll
    for (int sl = 0; sl < 32; ++sl) acc += part[(size_t)(b * 32 + sl) * WQ_ + t];
    out[b * WQ_ + t] = acc / z;
}

// ---------------------------------------------------------------------------
extern "C" void kernel_launch(void* const* d_in, const int* in_sizes, int n_in,
                              void* d_out, int out_size, void* d_ws, size_t ws_size,
                              hipStream_t stream) {
    const float* cx = (const float*)d_in[0];
    const float* gx = (const float*)d_in[1];
    const float* wx = (const float*)d_in[2];
    const float* Wc = (const float*)d_in[3];
    const float* bc = (const float*)d_in[4];
    const float* Wg = (const float*)d_in[5];
    const float* bg = (const float*)d_in[6];
    const float* Ww = (const float*)d_in[7];
    const float* bw = (const float*)d_in[8];
    const float* W1 = (const float*)d_in[9];
    const float* b1 = (const float*)d_in[10];
    const float* W2 = (const float*)d_in[11];
    const float* b2 = (const float*)d_in[12];
    float* out = (float*)d_out;

    // workspace layout
    float* ws        = (float*)d_ws;
    ushort* ws_w16   = (ushort*)ws;                      // M_*WQ_ fp16 (32 MB)
    float* ws_scores = ws + (size_t)M_ * WQ_ / 2;        // M_
    float* ws_base   = ws_scores + M_;                   // B_*H_
    float* ws_mz     = ws_base + B_ * H_;                // 2*B_
    float* ws_part   = ws_mz + 2 * B_;                   // B_*32*WQ_
    ushort* WwT16    = (ushort*)(ws_part + B_ * 32 * WQ_);   // W_*WQ_ fp16
    ushort* W1T16    = WwT16 + (size_t)W_ * WQ_;             // H_*H_ fp16

    convT16_kernel<<<(W_ / 64) * (WQ_ / 64), 256, 0, stream>>>(Ww, WwT16, W_, WQ_);
    convT16_kernel<<<(H_ / 64) * (H_ / 64), 256, 0, stream>>>(
        W1 + (size_t)(C_ + G_) * H_, W1T16, H_, H_);

    prep_kernel<<<B_, 256, 0, stream>>>(cx, gx, Wc, bc, Wg, bg, W1, b1, ws_base);

    gemm_w_mfma<<<M_ / 128, 512, 0, stream>>>(wx, WwT16, bw, ws_w16);

    gemm_scores_mfma<<<M_ / 128, 512, 0, stream>>>(
        ws_w16, W1T16, ws_base, W2, b2, ws_scores);

    softmax_stats_kernel<<<B_, 256, 0, stream>>>(ws_scores, ws_mz);

    weighted_partial_kernel<<<B_ * 32, 256, 0, stream>>>(ws_w16, ws_scores, ws_mz, ws_part);

    finalize_kernel<<<B_, 256, 0, stream>>>(ws_part, ws_mz, out);
}